// Round 2
// baseline (245.496 us; speedup 1.0000x reference)
//
#include <hip/hip_runtime.h>

#define DEV __device__ __forceinline__
#define KSIG (-1.442695041f)
#define KTANH (-2.885390082f)

typedef float f2 __attribute__((ext_vector_type(2)));
typedef float f4 __attribute__((ext_vector_type(4)));

DEV float fexp2(float x) { return __builtin_amdgcn_exp2f(x); }
DEV float frcp(float x) { return __builtin_amdgcn_rcpf(x); }
DEV float bperm(int a, float x) {
  return __int_as_float(__builtin_amdgcn_ds_bpermute(a, __float_as_int(x)));
}
DEV f2 pkfma(f2 a, f2 b, f2 c) { return __builtin_elementwise_fma(a, b, c); }

// Lane u of a 5-lane group owns state index j=u and gate rows
// {u,5+u,10+u,15+u} (i,f,g,o). kexp folded into weights/bias: sigmoid rows
// scaled by KSIG, g-row by KTANH; act = rcp(1+exp2(acc)), tanh = 2*act-1.
struct CellP {
  f2 wx[4][2];
  f2 wh[4][2];
  float wx4[4], wh4[4];
  f2 b2[4];  // {bias, 0}
};

DEV void load_cellP(CellP& W, int u, const float* __restrict__ Wih,
                    const float* __restrict__ Whh,
                    const float* __restrict__ bih,
                    const float* __restrict__ bhh) {
#pragma unroll
  for (int rt = 0; rt < 4; ++rt) {  // 0=i 1=f 2=g 3=o
    int row = 5 * rt + u;
    float kx = (rt == 2) ? KTANH : KSIG;
    W.wx[rt][0] = (f2){kx * Wih[row * 5 + 0], kx * Wih[row * 5 + 1]};
    W.wx[rt][1] = (f2){kx * Wih[row * 5 + 2], kx * Wih[row * 5 + 3]};
    W.wx4[rt] = kx * Wih[row * 5 + 4];
    W.wh[rt][0] = (f2){kx * Whh[row * 5 + 0], kx * Whh[row * 5 + 1]};
    W.wh[rt][1] = (f2){kx * Whh[row * 5 + 2], kx * Whh[row * 5 + 3]};
    W.wh4[rt] = kx * Whh[row * 5 + 4];
    W.b2[rt] = (f2){kx * (bih[row] + bhh[row]), 0.f};
  }
}

// One cell timestep; returns this lane's own h_j(t). hAll: h(t-1) in, h(t) out.
// Accumulation order: bias -> h-recurrent -> x-part. The x-part comes last so
// that when the "x" operand is a freshly-bpermuted value (the fused
// cell2a->cell2b handoff), its lgkmcnt wait lands at the END of the chain.
DEV float stepP(const CellP& W, const f2 xp[2], float x4, float hAll[5],
                float& c, const int bp[5]) {
  f2 hp0 = (f2){hAll[0], hAll[1]};
  f2 hp1 = (f2){hAll[2], hAll[3]};
  float acc[4];
#pragma unroll
  for (int rt = 0; rt < 4; ++rt) {
    f2 a2 = pkfma(W.wh[rt][0], hp0, W.b2[rt]);
    a2 = pkfma(W.wh[rt][1], hp1, a2);
    a2 = pkfma(W.wx[rt][0], xp[0], a2);
    a2 = pkfma(W.wx[rt][1], xp[1], a2);
    float a = a2.x + a2.y;
    a = fmaf(W.wh4[rt], hAll[4], a);
    acc[rt] = fmaf(W.wx4[rt], x4, a);
  }
  float gi = frcp(1.f + fexp2(acc[0]));
  float gf = frcp(1.f + fexp2(acc[1]));
  float gg = fmaf(2.f, frcp(1.f + fexp2(acc[2])), -1.f);
  float go = frcp(1.f + fexp2(acc[3]));
  c = fmaf(gf, c, gi * gg);
  float th = fmaf(2.f, frcp(1.f + fexp2(KTANH * c)), -1.f);
  float h = go * th;
#pragma unroll
  for (int u2 = 0; u2 < 5; ++u2) hAll[u2] = bperm(bp[u2], h);
  return h;
}

// 4-timestep x chunk: 20 floats = 5 aligned dwordx4 (elem base is 2560B
// aligned, chunks are 80B). Double-buffered, issued a full chunk (~4 steps of
// compute, >1200 busy cycles) ahead of first use -> covers ~900cy HBM latency.
struct XBuf {
  f4 a, b, c, d, e;
};

DEV void xload(XBuf& bf, const float* __restrict__ px, int ch) {
  const f4* q = (const f4*)px + ch * 5;
  bf.a = q[0];
  bf.b = q[1];
  bf.c = q[2];
  bf.d = q[3];
  bf.e = q[4];
}

// Step s of a chunk consumes floats [5s..5s+4]:
//  s=0: a.xyzw b.x   s=1: b.yzw c.xy   s=2: c.zw d.xyz   s=3: d.w e.xyzw

// Block = 192 threads = 3 waves, 24 elements. NO per-step barriers:
//   wave0: lstm1 for 24 elements (2 per 5-lane group, interleaved chains).
//   wave1: lstm2a+lstm2b fused in-lane for elements 0..11.
//   wave2: lstm2a+lstm2b fused in-lane for elements 12..23.
// __launch_bounds__(192,1): min 1 wave/EU -> full 512-VGPR budget so the
// allocator keeps the folded weights (96 floats for fused waves) RESIDENT
// instead of rematerializing/spilling them inside the recurrence loop
// (round-1's VGPR_Count=72 < live-value count proved it was thrashing).
__global__ __launch_bounds__(192, 1) void rnn_pf_kernel(
    const float* __restrict__ x1, const float* __restrict__ x2,
    const float* __restrict__ Wih1, const float* __restrict__ Whh1,
    const float* __restrict__ bih1, const float* __restrict__ bhh1,
    const float* __restrict__ Wih2a, const float* __restrict__ Whh2a,
    const float* __restrict__ bih2a, const float* __restrict__ bhh2a,
    const float* __restrict__ Wih2b, const float* __restrict__ Whh2b,
    const float* __restrict__ bih2b, const float* __restrict__ bhh2b,
    const float* __restrict__ W1, const float* __restrict__ b1,
    const float* __restrict__ W2, const float* __restrict__ b2,
    const float* __restrict__ W3, const float* __restrict__ b3,
    const float* __restrict__ W4, const float* __restrict__ b4,
    const float* __restrict__ W5, const float* __restrict__ b5,
    float* __restrict__ out, int B) {
  __shared__ float sIn[24][20];
  __shared__ float sA[24][32];
  __shared__ float sB[24][32];

  const int tid = threadIdx.x;
  const int w = tid >> 6;  // wave role: 0=lstm1 1=fused(0..11) 2=fused(12..23)
  const int l = tid & 63;
  int g = l / 5;
  const int u = l - 5 * g;
  const bool act = (g < 12);
  if (!act) g = 11;  // idle lanes 60..63 shadow group 11 (results discarded)
  const int base = blockIdx.x * 24;

  int bp[5];
#pragma unroll
  for (int k = 0; k < 5; ++k) bp[k] = (5 * g + k) * 4;

  if (w == 0) {
    // ---- lstm1, two independent elements per group for ILP ----
    CellP W;
    load_cellP(W, u, Wih1, Whh1, bih1, bhh1);
    const int e0 = base + 2 * g, e1 = e0 + 1;
    const int e0c = (e0 < B) ? e0 : B - 1;
    const int e1c = (e1 < B) ? e1 : B - 1;
    const float* p0 = x1 + (size_t)e0c * 640;
    const float* p1 = x1 + (size_t)e1c * 640;
    float h0[5], h1[5];
    float c0 = 0.f, c1 = 0.f, ho0 = 0.f, ho1 = 0.f;
#pragma unroll
    for (int k = 0; k < 5; ++k) {
      h0[k] = 0.f;
      h1[k] = 0.f;
    }

#define S1(xa, xb, xc, xd, xe, hh, cc, ho)       \
  do {                                           \
    f2 xin[2] = {(f2){xa, xb}, (f2){xc, xd}};    \
    ho = stepP(W, xin, xe, hh, cc, bp);          \
  } while (0)

#define CHUNK1(X0, X1)                                          \
  S1(X0.a.x, X0.a.y, X0.a.z, X0.a.w, X0.b.x, h0, c0, ho0);      \
  S1(X1.a.x, X1.a.y, X1.a.z, X1.a.w, X1.b.x, h1, c1, ho1);      \
  S1(X0.b.y, X0.b.z, X0.b.w, X0.c.x, X0.c.y, h0, c0, ho0);      \
  S1(X1.b.y, X1.b.z, X1.b.w, X1.c.x, X1.c.y, h1, c1, ho1);      \
  S1(X0.c.z, X0.c.w, X0.d.x, X0.d.y, X0.d.z, h0, c0, ho0);      \
  S1(X1.c.z, X1.c.w, X1.d.x, X1.d.y, X1.d.z, h1, c1, ho1);      \
  S1(X0.d.w, X0.e.x, X0.e.y, X0.e.z, X0.e.w, h0, c0, ho0);      \
  S1(X1.d.w, X1.e.x, X1.e.y, X1.e.z, X1.e.w, h1, c1, ho1)

    XBuf A0, B0, A1, B1;
    xload(A0, p0, 0);
    xload(A1, p1, 0);
    for (int ch = 0; ch < 32; ch += 2) {
      const int n1 = (ch + 1 < 32) ? ch + 1 : 31;
      xload(B0, p0, n1);
      xload(B1, p1, n1);
      CHUNK1(A0, A1);
      const int n2 = (ch + 2 < 32) ? ch + 2 : 31;
      xload(A0, p0, n2);
      xload(A1, p1, n2);
      CHUNK1(B0, B1);
    }
    if (act) {
      sIn[2 * g][u] = x1[(size_t)e0c * 640 + 635 + u];
      sIn[2 * g][10 + u] = ho0;  // h1(127)
      sIn[2 * g + 1][u] = x1[(size_t)e1c * 640 + 635 + u];
      sIn[2 * g + 1][10 + u] = ho1;
    }
  } else {
    // ---- lstm2 layer0 + layer1 fused in-lane: h2b(t) = cell2b(h2a(t)) ----
    CellP Wa, Wb;
    load_cellP(Wa, u, Wih2a, Whh2a, bih2a, bhh2a);
    load_cellP(Wb, u, Wih2b, Whh2b, bih2b, bhh2b);
    const int el = ((w == 1) ? 0 : 12) + g;
    const int e = base + el;
    const int ec = (e < B) ? e : B - 1;
    const float* px = x2 + (size_t)ec * 640;
    float hA[5], hB[5];
    float cA = 0.f, cB = 0.f, hoB = 0.f;
#pragma unroll
    for (int k = 0; k < 5; ++k) {
      hA[k] = 0.f;
      hB[k] = 0.f;
    }

#define SF(xa, xb, xc, xd, xe)                                  \
  do {                                                          \
    f2 xin[2] = {(f2){xa, xb}, (f2){xc, xd}};                   \
    (void)stepP(Wa, xin, xe, hA, cA, bp);                       \
    f2 hin[2] = {(f2){hA[0], hA[1]}, (f2){hA[2], hA[3]}};       \
    hoB = stepP(Wb, hin, hA[4], hB, cB, bp);                    \
  } while (0)

#define CHUNKF(X)                              \
  SF(X.a.x, X.a.y, X.a.z, X.a.w, X.b.x);       \
  SF(X.b.y, X.b.z, X.b.w, X.c.x, X.c.y);       \
  SF(X.c.z, X.c.w, X.d.x, X.d.y, X.d.z);       \
  SF(X.d.w, X.e.x, X.e.y, X.e.z, X.e.w)

    XBuf A, Bx;
    xload(A, px, 0);
    for (int ch = 0; ch < 32; ch += 2) {
      const int n1 = (ch + 1 < 32) ? ch + 1 : 31;
      xload(Bx, px, n1);
      CHUNKF(A);
      const int n2 = (ch + 2 < 32) ? ch + 2 : 31;
      xload(A, px, n2);
      CHUNKF(Bx);
    }
    if (act) {
      sIn[el][5 + u] = x2[(size_t)ec * 640 + 635 + u];
      sIn[el][15 + u] = hoB;  // h2b(127)
    }
  }
  __syncthreads();  // the ONLY lstm-phase barrier

  // FC stack: task-split over 192 lanes; weights from global (L1-cached).
  for (int task = tid; task < 24 * 32; task += 192) {
    int e = task >> 5, n = task & 31;
    float acc = b1[n];
#pragma unroll
    for (int k = 0; k < 20; ++k) acc = fmaf(W1[n * 20 + k], sIn[e][k], acc);
    sA[e][n] = fmaxf(acc, 0.f);
  }
  __syncthreads();
  for (int task = tid; task < 24 * 32; task += 192) {
    int e = task >> 5, n = task & 31;
    float acc = b2[n];
#pragma unroll
    for (int k = 0; k < 32; ++k) acc = fmaf(W2[n * 32 + k], sA[e][k], acc);
    sB[e][n] = fmaxf(acc, 0.f);
  }
  __syncthreads();
  for (int task = tid; task < 24 * 16; task += 192) {
    int e = task >> 4, n = task & 15;
    float acc = b3[n];
#pragma unroll
    for (int k = 0; k < 32; ++k) acc = fmaf(W3[n * 32 + k], sB[e][k], acc);
    sA[e][n] = fmaxf(acc, 0.f);  // reuse sA cols 0..15
  }
  __syncthreads();
  for (int task = tid; task < 24 * 16; task += 192) {
    int e = task >> 4, n = task & 15;
    float acc = b4[n];
#pragma unroll
    for (int k = 0; k < 16; ++k) acc = fmaf(W4[n * 16 + k], sA[e][k], acc);
    sB[e][n] = fmaxf(acc, 0.f);
  }
  __syncthreads();
  if (tid < 120) {  // 24 elems x 5 outputs
    int e = tid / 5, n = tid - 5 * (tid / 5);
    float acc = b5[n];
#pragma unroll
    for (int k = 0; k < 16; ++k) acc = fmaf(W5[n * 16 + k], sB[e][k], acc);
    int ego = base + e;
    if (ego < B) out[(size_t)ego * 5 + n] = acc;
  }
}

extern "C" void kernel_launch(void* const* d_in, const int* in_sizes, int n_in,
                              void* d_out, int out_size, void* d_ws,
                              size_t ws_size, hipStream_t stream) {
  const float* x1 = (const float*)d_in[0];
  const float* x2 = (const float*)d_in[1];
  const float* Wih1 = (const float*)d_in[2];
  const float* Whh1 = (const float*)d_in[3];
  const float* bih1 = (const float*)d_in[4];
  const float* bhh1 = (const float*)d_in[5];
  const float* Wih2a = (const float*)d_in[6];
  const float* Whh2a = (const float*)d_in[7];
  const float* bih2a = (const float*)d_in[8];
  const float* bhh2a = (const float*)d_in[9];
  const float* Wih2b = (const float*)d_in[10];
  const float* Whh2b = (const float*)d_in[11];
  const float* bih2b = (const float*)d_in[12];
  const float* bhh2b = (const float*)d_in[13];
  const float* W1 = (const float*)d_in[14];
  const float* b1 = (const float*)d_in[15];
  const float* W2 = (const float*)d_in[16];
  const float* b2 = (const float*)d_in[17];
  const float* W3 = (const float*)d_in[18];
  const float* b3 = (const float*)d_in[19];
  const float* W4 = (const float*)d_in[20];
  const float* b4 = (const float*)d_in[21];
  const float* W5 = (const float*)d_in[22];
  const float* b5 = (const float*)d_in[23];

  int B = in_sizes[0] / 640;  // [B,128,5]
  int nB = (B + 23) / 24;     // 24 elements per block

  rnn_pf_kernel<<<nB, 192, 0, stream>>>(
      x1, x2, Wih1, Whh1, bih1, bhh1, Wih2a, Whh2a, bih2a, bhh2a, Wih2b, Whh2b,
      bih2b, bhh2b, W1, b1, W2, b2, W3, b3, W4, b4, W5, b5, (float*)d_out, B);
}

// Round 3
// 237.773 us; speedup vs baseline: 1.0325x; 1.0325x over previous
//
#include <hip/hip_runtime.h>

#define DEV __device__ __forceinline__
#define KSIG (-1.442695041f)
#define KTANH (-2.885390082f)

typedef float f2 __attribute__((ext_vector_type(2)));

DEV float fexp2(float x) { return __builtin_amdgcn_exp2f(x); }
DEV float frcp(float x) { return __builtin_amdgcn_rcpf(x); }
DEV float bperm(int a, float x) {
  return __int_as_float(__builtin_amdgcn_ds_bpermute(a, __float_as_int(x)));
}
DEV f2 pkfma(f2 a, f2 b, f2 c) { return __builtin_elementwise_fma(a, b, c); }

// Lane u of a 5-lane group owns state index j=u and gate rows
// {u,5+u,10+u,15+u} (i,f,g,o). kexp folded into weights/bias: sigmoid rows
// scaled by KSIG, g-row by KTANH; act = rcp(1+exp2(acc)), tanh = 2*act-1.
struct CellP {
  f2 wx[4][2];
  f2 wh[4][2];
  float wx4[4], wh4[4];
  f2 b2[4];  // {bias, 0}
};

DEV void load_cellP(CellP& W, int u, const float* __restrict__ Wih,
                    const float* __restrict__ Whh,
                    const float* __restrict__ bih,
                    const float* __restrict__ bhh) {
#pragma unroll
  for (int rt = 0; rt < 4; ++rt) {  // 0=i 1=f 2=g 3=o
    int row = 5 * rt + u;
    float kx = (rt == 2) ? KTANH : KSIG;
    W.wx[rt][0] = (f2){kx * Wih[row * 5 + 0], kx * Wih[row * 5 + 1]};
    W.wx[rt][1] = (f2){kx * Wih[row * 5 + 2], kx * Wih[row * 5 + 3]};
    W.wx4[rt] = kx * Wih[row * 5 + 4];
    W.wh[rt][0] = (f2){kx * Whh[row * 5 + 0], kx * Whh[row * 5 + 1]};
    W.wh[rt][1] = (f2){kx * Whh[row * 5 + 2], kx * Whh[row * 5 + 3]};
    W.wh4[rt] = kx * Whh[row * 5 + 4];
    W.b2[rt] = (f2){kx * (bih[row] + bhh[row]), 0.f};
  }
}

// One cell timestep; returns this lane's own h_j(t). hAll: h(t-1) in, h(t) out.
// All bperm RESULTS are consumed only at the NEXT call with this hAll -> the
// compiler can sink the lgkmcnt wait to the consumer, off the critical path.
DEV float stepP(const CellP& W, const f2 xp[2], float x4, float hAll[5],
                float& c, const int bp[5]) {
  f2 hp0 = (f2){hAll[0], hAll[1]};
  f2 hp1 = (f2){hAll[2], hAll[3]};
  float acc[4];
#pragma unroll
  for (int rt = 0; rt < 4; ++rt) {
    f2 a2 = pkfma(W.wh[rt][0], hp0, W.b2[rt]);
    a2 = pkfma(W.wh[rt][1], hp1, a2);
    a2 = pkfma(W.wx[rt][0], xp[0], a2);
    a2 = pkfma(W.wx[rt][1], xp[1], a2);
    float a = a2.x + a2.y;
    a = fmaf(W.wh4[rt], hAll[4], a);
    acc[rt] = fmaf(W.wx4[rt], x4, a);
  }
  float gi = frcp(1.f + fexp2(acc[0]));
  float gf = frcp(1.f + fexp2(acc[1]));
  float gg = fmaf(2.f, frcp(1.f + fexp2(acc[2])), -1.f);
  float go = frcp(1.f + fexp2(acc[3]));
  c = fmaf(gf, c, gi * gg);
  float th = fmaf(2.f, frcp(1.f + fexp2(KTANH * c)), -1.f);
  float h = go * th;
#pragma unroll
  for (int u2 = 0; u2 < 5; ++u2) hAll[u2] = bperm(bp[u2], h);
  return h;
}

// Block = 192 threads = 3 waves, 24 elements. No per-step barriers.
//   wave0: lstm1 for 24 elements (2 per 5-lane group = 2 independent chains).
//   wave1/2: lstm2a+lstm2b fused, STAGGERED by one timestep: iteration t
//     computes cell2a(t) and cell2b(t-1), which are INDEPENDENT chains.
// Staggering halves the per-timestep dependence chain (rounds 1-2 showed the
// in-iteration 2a->2b chain was the long pole: 113/122/129us invariant with
// VALUBusy 40-50% across three sync structures = per-wave latency-bound).
__global__ __launch_bounds__(192, 2) void rnn_stag_kernel(
    const float* __restrict__ x1, const float* __restrict__ x2,
    const float* __restrict__ Wih1, const float* __restrict__ Whh1,
    const float* __restrict__ bih1, const float* __restrict__ bhh1,
    const float* __restrict__ Wih2a, const float* __restrict__ Whh2a,
    const float* __restrict__ bih2a, const float* __restrict__ bhh2a,
    const float* __restrict__ Wih2b, const float* __restrict__ Whh2b,
    const float* __restrict__ bih2b, const float* __restrict__ bhh2b,
    const float* __restrict__ W1, const float* __restrict__ b1,
    const float* __restrict__ W2, const float* __restrict__ b2,
    const float* __restrict__ W3, const float* __restrict__ b3,
    const float* __restrict__ W4, const float* __restrict__ b4,
    const float* __restrict__ W5, const float* __restrict__ b5,
    float* __restrict__ out, int B) {
  __shared__ float sIn[24][20];
  __shared__ float sA[24][32];
  __shared__ float sB[24][32];

  const int tid = threadIdx.x;
  const int w = tid >> 6;  // wave role: 0=lstm1 1=fused(0..11) 2=fused(12..23)
  const int l = tid & 63;
  int g = l / 5;
  const int u = l - 5 * g;
  const bool act = (g < 12);
  if (!act) g = 11;  // idle lanes 60..63 shadow group 11 (results discarded)
  const int base = blockIdx.x * 24;

  int bp[5];
#pragma unroll
  for (int k = 0; k < 5; ++k) bp[k] = (5 * g + k) * 4;

  if (w == 0) {
    // ---- lstm1, two independent elements per group for ILP ----
    CellP W;
    load_cellP(W, u, Wih1, Whh1, bih1, bhh1);
    const int e0 = base + 2 * g, e1 = e0 + 1;
    const int e0c = (e0 < B) ? e0 : B - 1;
    const int e1c = (e1 < B) ? e1 : B - 1;
    const float* p0 = x1 + (size_t)e0c * 640;
    const float* p1 = x1 + (size_t)e1c * 640;
    float h0[5], h1[5];
    float c0 = 0.f, c1 = 0.f, ho0 = 0.f, ho1 = 0.f;
#pragma unroll
    for (int k = 0; k < 5; ++k) {
      h0[k] = 0.f;
      h1[k] = 0.f;
    }
    f2 xa[2] = {(f2){p0[0], p0[1]}, (f2){p0[2], p0[3]}};
    f2 xb[2] = {(f2){p1[0], p1[1]}, (f2){p1[2], p1[3]}};
    float xa4 = p0[4], xb4 = p1[4];
    for (int t = 0; t < 128; ++t) {
      f2 xia[2] = {xa[0], xa[1]}, xib[2] = {xb[0], xb[1]};
      float xia4 = xa4, xib4 = xb4;
      const int tn = (t < 127) ? t + 1 : 127;  // prefetch x(t+1)
      xa[0] = (f2){p0[tn * 5 + 0], p0[tn * 5 + 1]};
      xa[1] = (f2){p0[tn * 5 + 2], p0[tn * 5 + 3]};
      xa4 = p0[tn * 5 + 4];
      xb[0] = (f2){p1[tn * 5 + 0], p1[tn * 5 + 1]};
      xb[1] = (f2){p1[tn * 5 + 2], p1[tn * 5 + 3]};
      xb4 = p1[tn * 5 + 4];
      ho0 = stepP(W, xia, xia4, h0, c0, bp);
      ho1 = stepP(W, xib, xib4, h1, c1, bp);
    }
    if (act) {
      sIn[2 * g][u] = x1[(size_t)e0c * 640 + 635 + u];
      sIn[2 * g][10 + u] = ho0;  // h1(127)
      sIn[2 * g + 1][u] = x1[(size_t)e1c * 640 + 635 + u];
      sIn[2 * g + 1][10 + u] = ho1;
    }
  } else {
    // ---- lstm2 layer0+layer1, staggered: iter t = {cell2a(t), cell2b(t-1)}
    CellP Wa, Wb;
    load_cellP(Wa, u, Wih2a, Whh2a, bih2a, bhh2a);
    load_cellP(Wb, u, Wih2b, Whh2b, bih2b, bhh2b);
    const int el = ((w == 1) ? 0 : 12) + g;
    const int e = base + el;
    const int ec = (e < B) ? e : B - 1;
    const float* px = x2 + (size_t)ec * 640;
    float hA[5], hB[5];
    float cA = 0.f, cB = 0.f, hoB = 0.f;
#pragma unroll
    for (int k = 0; k < 5; ++k) {
      hA[k] = 0.f;
      hB[k] = 0.f;
    }
    // prologue: cell2a at t=0
    f2 xc[2] = {(f2){px[0], px[1]}, (f2){px[2], px[3]}};
    float xc4 = px[4];
    (void)stepP(Wa, xc, xc4, hA, cA, bp);  // h2a(0)
    xc[0] = (f2){px[5], px[6]};
    xc[1] = (f2){px[7], px[8]};
    xc4 = px[9];
    for (int t = 1; t < 128; ++t) {
      f2 xin[2] = {xc[0], xc[1]};
      float xin4 = xc4;
      const int tn = (t < 127) ? t + 1 : 127;  // prefetch x2(t+1)
      xc[0] = (f2){px[tn * 5 + 0], px[tn * 5 + 1]};
      xc[1] = (f2){px[tn * 5 + 2], px[tn * 5 + 3]};
      xc4 = px[tn * 5 + 4];
      // capture h2a(t-1) before cell2a overwrites hAll
      f2 hin[2] = {(f2){hA[0], hA[1]}, (f2){hA[2], hA[3]}};
      float hin4 = hA[4];
      (void)stepP(Wa, xin, xin4, hA, cA, bp);  // h2a(t)   -- independent of:
      hoB = stepP(Wb, hin, hin4, hB, cB, bp);  // h2b(t-1)
    }
    {  // epilogue: h2b(127) from h2a(127)
      f2 hin[2] = {(f2){hA[0], hA[1]}, (f2){hA[2], hA[3]}};
      hoB = stepP(Wb, hin, hA[4], hB, cB, bp);
    }
    if (act) {
      sIn[el][5 + u] = x2[(size_t)ec * 640 + 635 + u];
      sIn[el][15 + u] = hoB;  // h2b(127)
    }
  }
  __syncthreads();  // the ONLY lstm-phase barrier

  // FC stack: task-split over 192 lanes; weights from global (L1-cached).
  for (int task = tid; task < 24 * 32; task += 192) {
    int e = task >> 5, n = task & 31;
    float acc = b1[n];
#pragma unroll
    for (int k = 0; k < 20; ++k) acc = fmaf(W1[n * 20 + k], sIn[e][k], acc);
    sA[e][n] = fmaxf(acc, 0.f);
  }
  __syncthreads();
  for (int task = tid; task < 24 * 32; task += 192) {
    int e = task >> 5, n = task & 31;
    float acc = b2[n];
#pragma unroll
    for (int k = 0; k < 32; ++k) acc = fmaf(W2[n * 32 + k], sA[e][k], acc);
    sB[e][n] = fmaxf(acc, 0.f);
  }
  __syncthreads();
  for (int task = tid; task < 24 * 16; task += 192) {
    int e = task >> 4, n = task & 15;
    float acc = b3[n];
#pragma unroll
    for (int k = 0; k < 32; ++k) acc = fmaf(W3[n * 32 + k], sB[e][k], acc);
    sA[e][n] = fmaxf(acc, 0.f);  // reuse sA cols 0..15
  }
  __syncthreads();
  for (int task = tid; task < 24 * 16; task += 192) {
    int e = task >> 4, n = task & 15;
    float acc = b4[n];
#pragma unroll
    for (int k = 0; k < 16; ++k) acc = fmaf(W4[n * 16 + k], sA[e][k], acc);
    sB[e][n] = fmaxf(acc, 0.f);
  }
  __syncthreads();
  if (tid < 120) {  // 24 elems x 5 outputs
    int e = tid / 5, n = tid - 5 * (tid / 5);
    float acc = b5[n];
#pragma unroll
    for (int k = 0; k < 16; ++k) acc = fmaf(W5[n * 16 + k], sB[e][k], acc);
    int ego = base + e;
    if (ego < B) out[(size_t)ego * 5 + n] = acc;
  }
}

extern "C" void kernel_launch(void* const* d_in, const int* in_sizes, int n_in,
                              void* d_out, int out_size, void* d_ws,
                              size_t ws_size, hipStream_t stream) {
  const float* x1 = (const float*)d_in[0];
  const float* x2 = (const float*)d_in[1];
  const float* Wih1 = (const float*)d_in[2];
  const float* Whh1 = (const float*)d_in[3];
  const float* bih1 = (const float*)d_in[4];
  const float* bhh1 = (const float*)d_in[5];
  const float* Wih2a = (const float*)d_in[6];
  const float* Whh2a = (const float*)d_in[7];
  const float* bih2a = (const float*)d_in[8];
  const float* bhh2a = (const float*)d_in[9];
  const float* Wih2b = (const float*)d_in[10];
  const float* Whh2b = (const float*)d_in[11];
  const float* bih2b = (const float*)d_in[12];
  const float* bhh2b = (const float*)d_in[13];
  const float* W1 = (const float*)d_in[14];
  const float* b1 = (const float*)d_in[15];
  const float* W2 = (const float*)d_in[16];
  const float* b2 = (const float*)d_in[17];
  const float* W3 = (const float*)d_in[18];
  const float* b3 = (const float*)d_in[19];
  const float* W4 = (const float*)d_in[20];
  const float* b4 = (const float*)d_in[21];
  const float* W5 = (const float*)d_in[22];
  const float* b5 = (const float*)d_in[23];

  int B = in_sizes[0] / 640;  // [B,128,5]
  int nB = (B + 23) / 24;     // 24 elements per block

  rnn_stag_kernel<<<nB, 192, 0, stream>>>(
      x1, x2, Wih1, Whh1, bih1, bhh1, Wih2a, Whh2a, bih2a, bhh2a, Wih2b, Whh2b,
      bih2b, bhh2b, W1, b1, W2, b2, W3, b3, W4, b4, W5, b5, (float*)d_out, B);
}

// Round 4
// 233.154 us; speedup vs baseline: 1.0529x; 1.0198x over previous
//
#include <hip/hip_runtime.h>

#define DEV __device__ __forceinline__
#define KSIG (-1.442695041f)
#define KTANH (-2.885390082f)

typedef float f2 __attribute__((ext_vector_type(2)));

DEV float fexp2(float x) { return __builtin_amdgcn_exp2f(x); }
DEV float frcp(float x) { return __builtin_amdgcn_rcpf(x); }
DEV float bperm(int a, float x) {
  return __int_as_float(__builtin_amdgcn_ds_bpermute(a, __float_as_int(x)));
}
DEV f2 pkfma(f2 a, f2 b, f2 c) { return __builtin_elementwise_fma(a, b, c); }

// Anti-rematerialization pins: values defined by volatile asm cannot be
// re-derived from memory loads, so the register allocator MUST keep them
// VGPR-resident across the recurrence loop. (Rounds 0-3: VGPR_Count 44-84 <
// the 48/96-float weight footprint => weights were being reloaded from L1/L2
// and re-folded EVERY cell-step, on the critical path. That was the ~115us
// invariant across four different sync structures.)
DEV void pinf(float& x) { asm volatile("" : "+v"(x)); }
DEV void pin2(f2& v) {
  float a = v.x, b = v.y;
  asm volatile("" : "+v"(a), "+v"(b));
  v = (f2){a, b};
}

// Lane u of a 5-lane group owns state index j=u and gate rows
// {u,5+u,10+u,15+u} (i,f,g,o). kexp folded into weights/bias: sigmoid rows
// scaled by KSIG, g-row by KTANH; act = rcp(1+exp2(acc)), tanh = 2*act-1.
struct CellP {
  f2 wx[4][2];
  f2 wh[4][2];
  float wx4[4], wh4[4];
  f2 b2[4];  // {bias, 0}
};

DEV void load_cellP(CellP& W, int u, const float* __restrict__ Wih,
                    const float* __restrict__ Whh,
                    const float* __restrict__ bih,
                    const float* __restrict__ bhh) {
#pragma unroll
  for (int rt = 0; rt < 4; ++rt) {  // 0=i 1=f 2=g 3=o
    int row = 5 * rt + u;
    float kx = (rt == 2) ? KTANH : KSIG;
    W.wx[rt][0] = (f2){kx * Wih[row * 5 + 0], kx * Wih[row * 5 + 1]};
    W.wx[rt][1] = (f2){kx * Wih[row * 5 + 2], kx * Wih[row * 5 + 3]};
    W.wx4[rt] = kx * Wih[row * 5 + 4];
    W.wh[rt][0] = (f2){kx * Whh[row * 5 + 0], kx * Whh[row * 5 + 1]};
    W.wh[rt][1] = (f2){kx * Whh[row * 5 + 2], kx * Whh[row * 5 + 3]};
    W.wh4[rt] = kx * Whh[row * 5 + 4];
    W.b2[rt] = (f2){kx * (bih[row] + bhh[row]), 0.f};
  }
#pragma unroll
  for (int rt = 0; rt < 4; ++rt) {  // pin everything resident
    pin2(W.wx[rt][0]);
    pin2(W.wx[rt][1]);
    pin2(W.wh[rt][0]);
    pin2(W.wh[rt][1]);
    pin2(W.b2[rt]);
    pinf(W.wx4[rt]);
    pinf(W.wh4[rt]);
  }
}

// One cell timestep; returns this lane's own h_j(t). hAll: h(t-1) in, h(t) out.
// All bperm RESULTS are consumed only at the NEXT call with this hAll -> the
// compiler can sink the lgkmcnt wait to the consumer, off the critical path.
DEV float stepP(const CellP& W, const f2 xp[2], float x4, float hAll[5],
                float& c, const int bp[5]) {
  f2 hp0 = (f2){hAll[0], hAll[1]};
  f2 hp1 = (f2){hAll[2], hAll[3]};
  float acc[4];
#pragma unroll
  for (int rt = 0; rt < 4; ++rt) {
    f2 a2 = pkfma(W.wh[rt][0], hp0, W.b2[rt]);
    a2 = pkfma(W.wh[rt][1], hp1, a2);
    a2 = pkfma(W.wx[rt][0], xp[0], a2);
    a2 = pkfma(W.wx[rt][1], xp[1], a2);
    float a = a2.x + a2.y;
    a = fmaf(W.wh4[rt], hAll[4], a);
    acc[rt] = fmaf(W.wx4[rt], x4, a);
  }
  float gi = frcp(1.f + fexp2(acc[0]));
  float gf = frcp(1.f + fexp2(acc[1]));
  float gg = fmaf(2.f, frcp(1.f + fexp2(acc[2])), -1.f);
  float go = frcp(1.f + fexp2(acc[3]));
  c = fmaf(gf, c, gi * gg);
  float th = fmaf(2.f, frcp(1.f + fexp2(KTANH * c)), -1.f);
  float h = go * th;
#pragma unroll
  for (int u2 = 0; u2 < 5; ++u2) hAll[u2] = bperm(bp[u2], h);
  return h;
}

// Block = 192 threads = 3 waves, 24 elements. No per-step barriers.
//   wave0: lstm1 for 24 elements (2 per 5-lane group = 2 independent chains).
//   wave1/2: lstm2a+lstm2b fused, STAGGERED by one timestep: iteration t
//     computes cell2a(t) and cell2b(t-1), which are INDEPENDENT chains.
// launch_bounds (192,2): VGPR cap 256 — fits the ~170 live values (weights
// now pinned resident) while keeping 2 waves/SIMD for latency hiding.
__global__ __launch_bounds__(192, 2) void rnn_pin_kernel(
    const float* __restrict__ x1, const float* __restrict__ x2,
    const float* __restrict__ Wih1, const float* __restrict__ Whh1,
    const float* __restrict__ bih1, const float* __restrict__ bhh1,
    const float* __restrict__ Wih2a, const float* __restrict__ Whh2a,
    const float* __restrict__ bih2a, const float* __restrict__ bhh2a,
    const float* __restrict__ Wih2b, const float* __restrict__ Whh2b,
    const float* __restrict__ bih2b, const float* __restrict__ bhh2b,
    const float* __restrict__ W1, const float* __restrict__ b1,
    const float* __restrict__ W2, const float* __restrict__ b2,
    const float* __restrict__ W3, const float* __restrict__ b3,
    const float* __restrict__ W4, const float* __restrict__ b4,
    const float* __restrict__ W5, const float* __restrict__ b5,
    float* __restrict__ out, int B) {
  __shared__ float sIn[24][20];
  __shared__ float sA[24][32];
  __shared__ float sB[24][32];

  const int tid = threadIdx.x;
  const int w = tid >> 6;  // wave role: 0=lstm1 1=fused(0..11) 2=fused(12..23)
  const int l = tid & 63;
  int g = l / 5;
  const int u = l - 5 * g;
  const bool act = (g < 12);
  if (!act) g = 11;  // idle lanes 60..63 shadow group 11 (results discarded)
  const int base = blockIdx.x * 24;

  int bp[5];
#pragma unroll
  for (int k = 0; k < 5; ++k) bp[k] = (5 * g + k) * 4;

  if (w == 0) {
    // ---- lstm1, two independent elements per group for ILP ----
    CellP W;
    load_cellP(W, u, Wih1, Whh1, bih1, bhh1);
    const int e0 = base + 2 * g, e1 = e0 + 1;
    const int e0c = (e0 < B) ? e0 : B - 1;
    const int e1c = (e1 < B) ? e1 : B - 1;
    const float* p0 = x1 + (size_t)e0c * 640;
    const float* p1 = x1 + (size_t)e1c * 640;
    float h0[5], h1[5];
    float c0 = 0.f, c1 = 0.f, ho0 = 0.f, ho1 = 0.f;
#pragma unroll
    for (int k = 0; k < 5; ++k) {
      h0[k] = 0.f;
      h1[k] = 0.f;
    }
    f2 xa[2] = {(f2){p0[0], p0[1]}, (f2){p0[2], p0[3]}};
    f2 xb[2] = {(f2){p1[0], p1[1]}, (f2){p1[2], p1[3]}};
    float xa4 = p0[4], xb4 = p1[4];
    for (int t = 0; t < 128; ++t) {
      f2 xia[2] = {xa[0], xa[1]}, xib[2] = {xb[0], xb[1]};
      float xia4 = xa4, xib4 = xb4;
      const int tn = (t < 127) ? t + 1 : 127;  // prefetch x(t+1)
      xa[0] = (f2){p0[tn * 5 + 0], p0[tn * 5 + 1]};
      xa[1] = (f2){p0[tn * 5 + 2], p0[tn * 5 + 3]};
      xa4 = p0[tn * 5 + 4];
      xb[0] = (f2){p1[tn * 5 + 0], p1[tn * 5 + 1]};
      xb[1] = (f2){p1[tn * 5 + 2], p1[tn * 5 + 3]};
      xb4 = p1[tn * 5 + 4];
      ho0 = stepP(W, xia, xia4, h0, c0, bp);
      ho1 = stepP(W, xib, xib4, h1, c1, bp);
    }
    if (act) {
      sIn[2 * g][u] = x1[(size_t)e0c * 640 + 635 + u];
      sIn[2 * g][10 + u] = ho0;  // h1(127)
      sIn[2 * g + 1][u] = x1[(size_t)e1c * 640 + 635 + u];
      sIn[2 * g + 1][10 + u] = ho1;
    }
  } else {
    // ---- lstm2 layer0+layer1, staggered: iter t = {cell2a(t), cell2b(t-1)}
    CellP Wa, Wb;
    load_cellP(Wa, u, Wih2a, Whh2a, bih2a, bhh2a);
    load_cellP(Wb, u, Wih2b, Whh2b, bih2b, bhh2b);
    const int el = ((w == 1) ? 0 : 12) + g;
    const int e = base + el;
    const int ec = (e < B) ? e : B - 1;
    const float* px = x2 + (size_t)ec * 640;
    float hA[5], hB[5];
    float cA = 0.f, cB = 0.f, hoB = 0.f;
#pragma unroll
    for (int k = 0; k < 5; ++k) {
      hA[k] = 0.f;
      hB[k] = 0.f;
    }
    // prologue: cell2a at t=0
    f2 xc[2] = {(f2){px[0], px[1]}, (f2){px[2], px[3]}};
    float xc4 = px[4];
    (void)stepP(Wa, xc, xc4, hA, cA, bp);  // h2a(0)
    xc[0] = (f2){px[5], px[6]};
    xc[1] = (f2){px[7], px[8]};
    xc4 = px[9];
    for (int t = 1; t < 128; ++t) {
      f2 xin[2] = {xc[0], xc[1]};
      float xin4 = xc4;
      const int tn = (t < 127) ? t + 1 : 127;  // prefetch x2(t+1)
      xc[0] = (f2){px[tn * 5 + 0], px[tn * 5 + 1]};
      xc[1] = (f2){px[tn * 5 + 2], px[tn * 5 + 3]};
      xc4 = px[tn * 5 + 4];
      // capture h2a(t-1) before cell2a overwrites hAll
      f2 hin[2] = {(f2){hA[0], hA[1]}, (f2){hA[2], hA[3]}};
      float hin4 = hA[4];
      (void)stepP(Wa, xin, xin4, hA, cA, bp);  // h2a(t)   -- independent of:
      hoB = stepP(Wb, hin, hin4, hB, cB, bp);  // h2b(t-1)
    }
    {  // epilogue: h2b(127) from h2a(127)
      f2 hin[2] = {(f2){hA[0], hA[1]}, (f2){hA[2], hA[3]}};
      hoB = stepP(Wb, hin, hA[4], hB, cB, bp);
    }
    if (act) {
      sIn[el][5 + u] = x2[(size_t)ec * 640 + 635 + u];
      sIn[el][15 + u] = hoB;  // h2b(127)
    }
  }
  __syncthreads();  // the ONLY lstm-phase barrier

  // FC stack: task-split over 192 lanes; weights from global (L1-cached).
  for (int task = tid; task < 24 * 32; task += 192) {
    int e = task >> 5, n = task & 31;
    float acc = b1[n];
#pragma unroll
    for (int k = 0; k < 20; ++k) acc = fmaf(W1[n * 20 + k], sIn[e][k], acc);
    sA[e][n] = fmaxf(acc, 0.f);
  }
  __syncthreads();
  for (int task = tid; task < 24 * 32; task += 192) {
    int e = task >> 5, n = task & 31;
    float acc = b2[n];
#pragma unroll
    for (int k = 0; k < 32; ++k) acc = fmaf(W2[n * 32 + k], sA[e][k], acc);
    sB[e][n] = fmaxf(acc, 0.f);
  }
  __syncthreads();
  for (int task = tid; task < 24 * 16; task += 192) {
    int e = task >> 4, n = task & 15;
    float acc = b3[n];
#pragma unroll
    for (int k = 0; k < 32; ++k) acc = fmaf(W3[n * 32 + k], sB[e][k], acc);
    sA[e][n] = fmaxf(acc, 0.f);  // reuse sA cols 0..15
  }
  __syncthreads();
  for (int task = tid; task < 24 * 16; task += 192) {
    int e = task >> 4, n = task & 15;
    float acc = b4[n];
#pragma unroll
    for (int k = 0; k < 16; ++k) acc = fmaf(W4[n * 16 + k], sA[e][k], acc);
    sB[e][n] = fmaxf(acc, 0.f);
  }
  __syncthreads();
  if (tid < 120) {  // 24 elems x 5 outputs
    int e = tid / 5, n = tid - 5 * (tid / 5);
    float acc = b5[n];
#pragma unroll
    for (int k = 0; k < 16; ++k) acc = fmaf(W5[n * 16 + k], sB[e][k], acc);
    int ego = base + e;
    if (ego < B) out[(size_t)ego * 5 + n] = acc;
  }
}

extern "C" void kernel_launch(void* const* d_in, const int* in_sizes, int n_in,
                              void* d_out, int out_size, void* d_ws,
                              size_t ws_size, hipStream_t stream) {
  const float* x1 = (const float*)d_in[0];
  const float* x2 = (const float*)d_in[1];
  const float* Wih1 = (const float*)d_in[2];
  const float* Whh1 = (const float*)d_in[3];
  const float* bih1 = (const float*)d_in[4];
  const float* bhh1 = (const float*)d_in[5];
  const float* Wih2a = (const float*)d_in[6];
  const float* Whh2a = (const float*)d_in[7];
  const float* bih2a = (const float*)d_in[8];
  const float* bhh2a = (const float*)d_in[9];
  const float* Wih2b = (const float*)d_in[10];
  const float* Whh2b = (const float*)d_in[11];
  const float* bih2b = (const float*)d_in[12];
  const float* bhh2b = (const float*)d_in[13];
  const float* W1 = (const float*)d_in[14];
  const float* b1 = (const float*)d_in[15];
  const float* W2 = (const float*)d_in[16];
  const float* b2 = (const float*)d_in[17];
  const float* W3 = (const float*)d_in[18];
  const float* b3 = (const float*)d_in[19];
  const float* W4 = (const float*)d_in[20];
  const float* b4 = (const float*)d_in[21];
  const float* W5 = (const float*)d_in[22];
  const float* b5 = (const float*)d_in[23];

  int B = in_sizes[0] / 640;  // [B,128,5]
  int nB = (B + 23) / 24;     // 24 elements per block

  rnn_pin_kernel<<<nB, 192, 0, stream>>>(
      x1, x2, Wih1, Whh1, bih1, bhh1, Wih2a, Whh2a, bih2a, bhh2a, Wih2b, Whh2b,
      bih2b, bhh2b, W1, b1, W2, b2, W3, b3, W4, b4, W5, b5, (float*)d_out, B);
}

// Round 6
// 231.731 us; speedup vs baseline: 1.0594x; 1.0061x over previous
//
#include <hip/hip_runtime.h>

#define DEV __device__ __forceinline__
#define KSIG (-1.442695041f)
#define KTANH (-2.885390082f)

typedef float f2 __attribute__((ext_vector_type(2)));
typedef float f4 __attribute__((ext_vector_type(4)));

DEV float fexp2(float x) { return __builtin_amdgcn_exp2f(x); }
DEV float frcp(float x) { return __builtin_amdgcn_rcpf(x); }
DEV f2 pkfma(f2 a, f2 b, f2 c) { return __builtin_elementwise_fma(a, b, c); }

DEV void pin2(f2& v) {
  float a = v.x, b = v.y;
  asm volatile("" : "+v"(a), "+v"(b));
  v = (f2){a, b};
}

// lgkmcnt-only barrier: orders LDS ops across waves WITHOUT draining vmcnt,
// so the global x-prefetch stays in flight across per-timestep syncs.
// (__syncthreads emits s_waitcnt vmcnt(0) lgkmcnt(0) and would serialize it.)
// Executed in wave-uniform control flow exactly 128x by each of 3 waves.
DEV void sync_lds() {
  asm volatile("s_waitcnt lgkmcnt(0)\ns_barrier" ::: "memory");
}

// ELEMENT-PER-LANE cell: each lane owns one batch element; h[5],c[5] live
// in-lane (NO cross-lane ops in the recurrence). Weights are wave-uniform,
// packed as f2 gate-pairs: p=0 -> {i_j, f_j} rows (both sigmoid, KSIG-folded),
// p=1 -> {g_j, o_j} rows (tanh KTANH / sigmoid KSIG). 110 f2 = 220 VGPRs.
struct CellU {
  f2 wx[2][5][5];  // [p][j][k]
  f2 wh[2][5][5];
  f2 bb[2][5];
};

DEV void load_cellU(CellU& W, const float* __restrict__ Wih,
                    const float* __restrict__ Whh,
                    const float* __restrict__ bih,
                    const float* __restrict__ bhh) {
#pragma unroll
  for (int j = 0; j < 5; ++j) {
#pragma unroll
    for (int k = 0; k < 5; ++k) {
      W.wx[0][j][k] = (f2){KSIG * Wih[j * 5 + k], KSIG * Wih[(5 + j) * 5 + k]};
      W.wx[1][j][k] =
          (f2){KTANH * Wih[(10 + j) * 5 + k], KSIG * Wih[(15 + j) * 5 + k]};
      W.wh[0][j][k] = (f2){KSIG * Whh[j * 5 + k], KSIG * Whh[(5 + j) * 5 + k]};
      W.wh[1][j][k] =
          (f2){KTANH * Whh[(10 + j) * 5 + k], KSIG * Whh[(15 + j) * 5 + k]};
    }
    W.bb[0][j] =
        (f2){KSIG * (bih[j] + bhh[j]), KSIG * (bih[5 + j] + bhh[5 + j])};
    W.bb[1][j] = (f2){KTANH * (bih[10 + j] + bhh[10 + j]),
                      KSIG * (bih[15 + j] + bhh[15 + j])};
  }
}

// One timestep, fully in-lane. 100 pk_fma + activations.
DEV void stepU(const CellU& W, float x0, float x1, float x2, float x3, float x4,
               float h[5], float c[5]) {
  f2 aIF[5], aGO[5];
#pragma unroll
  for (int j = 0; j < 5; ++j) {
    aIF[j] = W.bb[0][j];
    aGO[j] = W.bb[1][j];
  }
  float xs[5] = {x0, x1, x2, x3, x4};
#pragma unroll
  for (int k = 0; k < 5; ++k) {
    f2 xk = (f2){xs[k], xs[k]};
#pragma unroll
    for (int j = 0; j < 5; ++j) {
      aIF[j] = pkfma(W.wx[0][j][k], xk, aIF[j]);
      aGO[j] = pkfma(W.wx[1][j][k], xk, aGO[j]);
    }
  }
#pragma unroll
  for (int k = 0; k < 5; ++k) {
    f2 hk = (f2){h[k], h[k]};
#pragma unroll
    for (int j = 0; j < 5; ++j) {
      aIF[j] = pkfma(W.wh[0][j][k], hk, aIF[j]);
      aGO[j] = pkfma(W.wh[1][j][k], hk, aGO[j]);
    }
  }
#pragma unroll
  for (int j = 0; j < 5; ++j) {
    float gi = frcp(1.f + fexp2(aIF[j].x));
    float gf = frcp(1.f + fexp2(aIF[j].y));
    float tg = fmaf(2.f, frcp(1.f + fexp2(aGO[j].x)), -1.f);
    float go = frcp(1.f + fexp2(aGO[j].y));
    c[j] = fmaf(gf, c[j], gi * tg);
    float tc = fmaf(2.f, frcp(1.f + fexp2(KTANH * c[j])), -1.f);
    h[j] = go * tc;
  }
}

// 4-timestep x chunk (20 floats = 5 aligned dwordx4), double-buffered.
struct XBuf {
  f4 a, b, c, d, e;
};
DEV void xload(XBuf& bf, const float* __restrict__ px, int ch) {
  const f4* q = (const f4*)px + ch * 5;
  bf.a = q[0];
  bf.b = q[1];
  bf.c = q[2];
  bf.d = q[3];
  bf.e = q[4];
}

// One timestep of the 3-wave pipeline. S = step-in-chunk (compile-time), so
// sH parities are compile-time. w2 consumes h2a(t-1); w1 publishes h2a(t).
#define STEP_S(S, RST, X0, X1, X2, X3, X4)                 \
  {                                                        \
    float xv0, xv1, xv2, xv3, xv4;                         \
    if (w == 2) {                                          \
      const int rb = ((S) + 1) & 1;                        \
      xv0 = sH[rb][l][0];                                  \
      xv1 = sH[rb][l][1];                                  \
      xv2 = sH[rb][l][2];                                  \
      xv3 = sH[rb][l][3];                                  \
      xv4 = sH[rb][l][4];                                  \
    } else {                                               \
      xv0 = X0;                                            \
      xv1 = X1;                                            \
      xv2 = X2;                                            \
      xv3 = X3;                                            \
      xv4 = X4;                                            \
    }                                                      \
    stepU(W, xv0, xv1, xv2, xv3, xv4, h, c);               \
    if (w == 1) {                                          \
      const int wb = (S) & 1;                              \
      sH[wb][l][0] = h[0];                                 \
      sH[wb][l][1] = h[1];                                 \
      sH[wb][l][2] = h[2];                                 \
      sH[wb][l][3] = h[3];                                 \
      sH[wb][l][4] = h[4];                                 \
    }                                                      \
    if ((RST) && w == 2) { /* discard junk step at t==0 */ \
      h[0] = h[1] = h[2] = h[3] = h[4] = 0.f;              \
      c[0] = c[1] = c[2] = c[3] = c[4] = 0.f;              \
    }                                                      \
    sync_lds();                                            \
  }

#define CHUNK(X, RST)                                 \
  STEP_S(0, RST, X.a.x, X.a.y, X.a.z, X.a.w, X.b.x)   \
  STEP_S(1, false, X.b.y, X.b.z, X.b.w, X.c.x, X.c.y) \
  STEP_S(2, false, X.c.z, X.c.w, X.d.x, X.d.y, X.d.z) \
  STEP_S(3, false, X.d.w, X.e.x, X.e.y, X.e.z, X.e.w)

// Block = 192 threads = 3 waves, 64 elements (one per lane, no idle lanes).
//   wave0: lstm1(x1)   wave1: lstm2a(x2)   wave2: lstm2b(h2a via sH ring)
// 256 blocks = 1 block/CU; each wave alone on a SIMD with ~300 VGPRs of
// uniform weights + state. Recurrence chain is pure in-lane FMA/trans.
__global__ __launch_bounds__(192, 1) void rnn_epl_kernel(
    const float* __restrict__ x1, const float* __restrict__ x2,
    const float* __restrict__ Wih1, const float* __restrict__ Whh1,
    const float* __restrict__ bih1, const float* __restrict__ bhh1,
    const float* __restrict__ Wih2a, const float* __restrict__ Whh2a,
    const float* __restrict__ bih2a, const float* __restrict__ bhh2a,
    const float* __restrict__ Wih2b, const float* __restrict__ Whh2b,
    const float* __restrict__ bih2b, const float* __restrict__ bhh2b,
    const float* __restrict__ W1, const float* __restrict__ b1,
    const float* __restrict__ W2, const float* __restrict__ b2,
    const float* __restrict__ W3, const float* __restrict__ b3,
    const float* __restrict__ W4, const float* __restrict__ b4,
    const float* __restrict__ W5, const float* __restrict__ b5,
    float* __restrict__ out, int B) {
  __shared__ float sH[2][64][5];  // h2a ring (stride 5 words: conflict-free)
  __shared__ float sIn[64][20];
  __shared__ float sA[64][32];
  __shared__ float sB[64][32];

  const int tid = threadIdx.x;
  const int w = tid >> 6;  // 0=lstm1 1=lstm2a 2=lstm2b
  const int l = tid & 63;
  const int e = blockIdx.x * 64 + l;
  const int ec = (e < B) ? e : (B - 1);

  CellU W;
  if (w == 0)
    load_cellU(W, Wih1, Whh1, bih1, bhh1);
  else if (w == 1)
    load_cellU(W, Wih2a, Whh2a, bih2a, bhh2a);
  else
    load_cellU(W, Wih2b, Whh2b, bih2b, bhh2b);
#pragma unroll
  for (int p = 0; p < 2; ++p) {
#pragma unroll
    for (int j = 0; j < 5; ++j) {
#pragma unroll
      for (int k = 0; k < 5; ++k) {
        pin2(W.wx[p][j][k]);
        pin2(W.wh[p][j][k]);
      }
      pin2(W.bb[p][j]);
    }
  }

  const float* px = ((w == 0) ? x1 : x2) + (size_t)ec * 640;

  for (int i = tid; i < 2 * 64 * 5; i += 192) ((float*)sH)[i] = 0.f;

  float h[5], c[5];
#pragma unroll
  for (int j = 0; j < 5; ++j) {
    h[j] = 0.f;
    c[j] = 0.f;
  }

  XBuf cur{}, nxt{};
  if (w < 2) xload(cur, px, 0);
  __syncthreads();  // sH zeroed + first chunk ordering

  for (int ch = 0; ch < 32; ch += 2) {
    if (w < 2) xload(nxt, px, ch + 1);
    const bool rst = (ch == 0);
    CHUNK(cur, rst);
    if (w < 2) xload(cur, px, (ch + 2 < 32) ? ch + 2 : 31);
    CHUNK(nxt, false);
  }

  if (w == 2) {  // trail step: h2b(127) from h2a(127) in sH[127&1]=sH[1]
    stepU(W, sH[1][l][0], sH[1][l][1], sH[1][l][2], sH[1][l][3], sH[1][l][4],
          h, c);
  }

  // Stage FC inputs: [x1_last, x2_last, h1, h2b]
  if (w == 0) {
#pragma unroll
    for (int k = 0; k < 5; ++k) sIn[l][k] = px[635 + k];
#pragma unroll
    for (int j = 0; j < 5; ++j) sIn[l][10 + j] = h[j];
  } else if (w == 1) {
#pragma unroll
    for (int k = 0; k < 5; ++k) sIn[l][5 + k] = px[635 + k];
  } else {
#pragma unroll
    for (int j = 0; j < 5; ++j) sIn[l][15 + j] = h[j];
  }
  __syncthreads();

  // FC stack: task-split over 192 lanes; weights from global (L1-cached).
  for (int task = tid; task < 64 * 32; task += 192) {
    int e2 = task >> 5, n = task & 31;
    float acc = b1[n];
#pragma unroll
    for (int k = 0; k < 20; ++k) acc = fmaf(W1[n * 20 + k], sIn[e2][k], acc);
    sA[e2][n] = fmaxf(acc, 0.f);
  }
  __syncthreads();
  for (int task = tid; task < 64 * 32; task += 192) {
    int e2 = task >> 5, n = task & 31;
    float acc = b2[n];
#pragma unroll
    for (int k = 0; k < 32; ++k) acc = fmaf(W2[n * 32 + k], sA[e2][k], acc);
    sB[e2][n] = fmaxf(acc, 0.f);
  }
  __syncthreads();
  for (int task = tid; task < 64 * 16; task += 192) {
    int e2 = task >> 4, n = task & 15;
    float acc = b3[n];
#pragma unroll
    for (int k = 0; k < 32; ++k) acc = fmaf(W3[n * 32 + k], sB[e2][k], acc);
    sA[e2][n] = fmaxf(acc, 0.f);  // reuse sA cols 0..15
  }
  __syncthreads();
  for (int task = tid; task < 64 * 16; task += 192) {
    int e2 = task >> 4, n = task & 15;
    float acc = b4[n];
#pragma unroll
    for (int k = 0; k < 16; ++k) acc = fmaf(W4[n * 16 + k], sA[e2][k], acc);
    sB[e2][n] = fmaxf(acc, 0.f);
  }
  __syncthreads();
  for (int task = tid; task < 64 * 5; task += 192) {
    int e2 = task / 5, n = task - 5 * (task / 5);
    float acc = b5[n];
#pragma unroll
    for (int k = 0; k < 16; ++k) acc = fmaf(W5[n * 16 + k], sB[e2][k], acc);
    int ego = blockIdx.x * 64 + e2;
    if (ego < B) out[(size_t)ego * 5 + n] = acc;
  }
}

extern "C" void kernel_launch(void* const* d_in, const int* in_sizes, int n_in,
                              void* d_out, int out_size, void* d_ws,
                              size_t ws_size, hipStream_t stream) {
  const float* x1 = (const float*)d_in[0];
  const float* x2 = (const float*)d_in[1];
  const float* Wih1 = (const float*)d_in[2];
  const float* Whh1 = (const float*)d_in[3];
  const float* bih1 = (const float*)d_in[4];
  const float* bhh1 = (const float*)d_in[5];
  const float* Wih2a = (const float*)d_in[6];
  const float* Whh2a = (const float*)d_in[7];
  const float* bih2a = (const float*)d_in[8];
  const float* bhh2a = (const float*)d_in[9];
  const float* Wih2b = (const float*)d_in[10];
  const float* Whh2b = (const float*)d_in[11];
  const float* bih2b = (const float*)d_in[12];
  const float* bhh2b = (const float*)d_in[13];
  const float* W1 = (const float*)d_in[14];
  const float* b1 = (const float*)d_in[15];
  const float* W2 = (const float*)d_in[16];
  const float* b2 = (const float*)d_in[17];
  const float* W3 = (const float*)d_in[18];
  const float* b3 = (const float*)d_in[19];
  const float* W4 = (const float*)d_in[20];
  const float* b4 = (const float*)d_in[21];
  const float* W5 = (const float*)d_in[22];
  const float* b5 = (const float*)d_in[23];

  int B = in_sizes[0] / 640;  // [B,128,5]
  int nB = (B + 63) / 64;     // 64 elements per block

  rnn_epl_kernel<<<nB, 192, 0, stream>>>(
      x1, x2, Wih1, Whh1, bih1, bhh1, Wih2a, Whh2a, bih2a, bhh2a, Wih2b, Whh2b,
      bih2b, bhh2b, W1, b1, W2, b2, W3, b3, W4, b4, W5, b5, (float*)d_out, B);
}